// Round 5
// baseline (19111.055 us; speedup 1.0000x reference)
//
#include <hip/hip_runtime.h>
#include <cstddef>

#define BB 32
#define TT 512
#define HH 512
#define NBLK 256
#define AG __HIP_MEMORY_SCOPE_AGENT

// ---------------------------------------------------------------------------
// Persistent-kernel GRU, 2 layers software-pipelined (layer 1 lags 1 step).
//
// Coherence protocol (the round-1 fix):
//   - state writes (h, rh, uu, y0): relaxed AGENT-scope atomic stores ->
//     sc-flagged, write-through to coherence point; L2 never holds dirty state.
//   - barrier: __syncthreads (drains vmcnt) -> relaxed atomicAdd -> relaxed
//     spin -> ONE acquire load (waitcnt + buffer_inv; invalidate-only, cheap).
//   - state reads after barrier: PLAIN cached loads (fresh post-inv, then
//     L2-cached so cross-block row duplication is served by per-XCD L2).
//   - x / weights / biases: immutable -> plain cached loads everywhere.
//
// Work decomposition (col-parallel, weights VGPR-resident for the whole run):
//   256 blocks x 256 thr. l = blk>>7, cg = blk&127.
//   gates: cols [cg*8, cg*8+8);  wave w -> batches [w*8, w*8+8).
//          K=1024 split over 64 lanes (16 floats each; lanes<32 = x|y0 half,
//          lanes>=32 = h half). 8 accs reduced with select-merge butterfly:
//          after red8, lane L holds col (cg*8 + (L&7))'s full dot.
//   cand : cols [cg*4, cg*4+4); same batch split; red4 -> col cg*4 + (L&3).
//   Weights: 8 gate cols (128 VGPR) + 4 cand cols (64 VGPR) per lane, loaded
//   once from the transposed copies; zero per-step weight traffic.
//
// ws (floats): h0@0[16384] h1@16384 y0@32768[2][32][512] rh@65536[2][32][512]
//              uu@98304 bar(int)@131072; weights WgT@131088, WcT@2228240.
// ---------------------------------------------------------------------------

template <int R, int C>
__global__ __launch_bounds__(256) void transpose_k(const float* __restrict__ src,
                                                   float* __restrict__ dst) {
    __shared__ float tile[32][33];
    const int tx = threadIdx.x & 31;
    const int ty = threadIdx.x >> 5;
    const int tiles_c = C / 32;
    const int bc_ = blockIdx.x % tiles_c;
    const int br_ = blockIdx.x / tiles_c;
    const int r0 = br_ * 32, c0 = bc_ * 32;
#pragma unroll
    for (int k = 0; k < 32; k += 8)
        tile[ty + k][tx] = src[(size_t)(r0 + ty + k) * C + (c0 + tx)];
    __syncthreads();
#pragma unroll
    for (int k = 0; k < 32; k += 8)
        dst[(size_t)(c0 + ty + k) * R + (r0 + tx)] = tile[tx][ty + k];
}

__device__ __forceinline__ float dot16(const float4& a0, const float4& a1,
                                       const float4& a2, const float4& a3,
                                       const float4* W) {
    float s0 = a0.x * W[0].x + a0.y * W[0].y + a0.z * W[0].z + a0.w * W[0].w;
    float s1 = a1.x * W[1].x + a1.y * W[1].y + a1.z * W[1].z + a1.w * W[1].w;
    float s2 = a2.x * W[2].x + a2.y * W[2].y + a2.z * W[2].z + a2.w * W[2].w;
    float s3 = a3.x * W[3].x + a3.y * W[3].y + a3.z * W[3].z + a3.w * W[3].w;
    return (s0 + s1) + (s2 + s3);
}

// Reduce 8 accumulators over 64 lanes; returns total of acc[lane&7] on every lane.
__device__ __forceinline__ float red8(float a0, float a1, float a2, float a3,
                                      float a4, float a5, float a6, float a7,
                                      int lane) {
    const bool b1 = lane & 1, b2 = lane & 2, b4 = lane & 4;
    float p0 = (b1 ? a1 : a0) + __shfl_xor((b1 ? a0 : a1), 1, 64);
    float p1 = (b1 ? a3 : a2) + __shfl_xor((b1 ? a2 : a3), 1, 64);
    float p2 = (b1 ? a5 : a4) + __shfl_xor((b1 ? a4 : a5), 1, 64);
    float p3 = (b1 ? a7 : a6) + __shfl_xor((b1 ? a6 : a7), 1, 64);
    float q0 = (b2 ? p1 : p0) + __shfl_xor((b2 ? p0 : p1), 2, 64);
    float q1 = (b2 ? p3 : p2) + __shfl_xor((b2 ? p2 : p3), 2, 64);
    float r = (b4 ? q1 : q0) + __shfl_xor((b4 ? q0 : q1), 4, 64);
    r += __shfl_xor(r, 8, 64);
    r += __shfl_xor(r, 16, 64);
    r += __shfl_xor(r, 32, 64);
    return r;
}

// Reduce 4 accumulators over 64 lanes; returns total of acc[lane&3] on every lane.
__device__ __forceinline__ float red4(float a0, float a1, float a2, float a3,
                                      int lane) {
    const bool b1 = lane & 1, b2 = lane & 2;
    float p0 = (b1 ? a1 : a0) + __shfl_xor((b1 ? a0 : a1), 1, 64);
    float p1 = (b1 ? a3 : a2) + __shfl_xor((b1 ? a2 : a3), 1, 64);
    float r = (b2 ? p1 : p0) + __shfl_xor((b2 ? p0 : p1), 2, 64);
    r += __shfl_xor(r, 4, 64);
    r += __shfl_xor(r, 8, 64);
    r += __shfl_xor(r, 16, 64);
    r += __shfl_xor(r, 32, 64);
    return r;
}

__device__ __forceinline__ void stc(float* p, float v) {
    __hip_atomic_store(p, v, __ATOMIC_RELAXED, AG);
}

__device__ __forceinline__ void gbar(int* bar, int tgt) {
    __syncthreads();  // compiler drains vmcnt(0) before s_barrier -> stores done
    if (threadIdx.x == 0) {
        __hip_atomic_fetch_add(bar, 1, __ATOMIC_RELAXED, AG);
        while (__hip_atomic_load(bar, __ATOMIC_RELAXED, AG) < tgt)
            __builtin_amdgcn_s_sleep(2);
        (void)__hip_atomic_load(bar, __ATOMIC_ACQUIRE, AG);  // waitcnt + inv
    }
    __syncthreads();
}

__global__ __launch_bounds__(256, 1) void rnn_persist(
    const float* __restrict__ x, const int* __restrict__ seq_lens,
    const float* __restrict__ WgT, const float* __restrict__ bg,
    const float* __restrict__ WcT, const float* __restrict__ bc,
    float* __restrict__ out, float* __restrict__ ws) {
    float* h0 = ws;
    float* h1 = ws + 16384;
    float* y0 = ws + 32768;
    float* rh = ws + 65536;
    float* uu = ws + 98304;
    int* bar = (int*)(ws + 131072);

    const int l = blockIdx.x >> 7;
    const int cg = blockIdx.x & 127;
    const int w = threadIdx.x >> 6;
    const int lane = threadIdx.x & 63;
    const int gj0 = cg * 8;
    const int cj0 = cg * 4;

    float* __restrict__ hl = l ? h1 : h0;
    float* __restrict__ rhl = rh + (size_t)l * (BB * HH);
    float* __restrict__ uul = uu + (size_t)l * (BB * HH);

    // persistent per-lane weight slices (k in [lane*16, lane*16+16))
    float4 WG[8][4];
    {
        const float* p = WgT + ((size_t)(l * 1024 + gj0)) * 1024 + lane * 16;
#pragma unroll
        for (int c = 0; c < 8; ++c)
#pragma unroll
            for (int q = 0; q < 4; ++q)
                WG[c][q] = *(const float4*)(p + (size_t)c * 1024 + q * 4);
    }
    float4 WC[4][4];
    {
        const float* p = WcT + ((size_t)(l * 512 + cj0)) * 1024 + lane * 16;
#pragma unroll
        for (int c = 0; c < 4; ++c)
#pragma unroll
            for (int q = 0; q < 4; ++q)
                WC[c][q] = *(const float4*)(p + (size_t)c * 1024 + q * 4);
    }
    const float bgj = bg[l * 1024 + gj0 + (lane & 7)];
    const float bcm = bc[l * 512 + cj0 + (lane & 3)];

    int tgt = NBLK;
    for (int t = 0; t <= TT; ++t) {
        const int tt = t - l;
        const bool active = (tt >= 0) && (tt < TT);

        // ---------------- phase A: gates ----------------
        if (active) {
#pragma unroll 2
            for (int bi = 0; bi < 8; ++bi) {
                const int b = w * 8 + bi;
                const float* inrow = l ? (y0 + ((size_t)((tt & 1) * BB + b)) * HH)
                                       : (x + ((size_t)b * TT + tt) * HH);
                const float* vp = (lane < 32) ? (inrow + lane * 16)
                                              : (hl + (size_t)b * HH + (lane - 32) * 16);
                const float4 a0 = ((const float4*)vp)[0];
                const float4 a1 = ((const float4*)vp)[1];
                const float4 a2 = ((const float4*)vp)[2];
                const float4 a3 = ((const float4*)vp)[3];
                const float s0 = dot16(a0, a1, a2, a3, WG[0]);
                const float s1 = dot16(a0, a1, a2, a3, WG[1]);
                const float s2 = dot16(a0, a1, a2, a3, WG[2]);
                const float s3 = dot16(a0, a1, a2, a3, WG[3]);
                const float s4 = dot16(a0, a1, a2, a3, WG[4]);
                const float s5 = dot16(a0, a1, a2, a3, WG[5]);
                const float s6 = dot16(a0, a1, a2, a3, WG[6]);
                const float s7 = dot16(a0, a1, a2, a3, WG[7]);
                const float sum = red8(s0, s1, s2, s3, s4, s5, s6, s7, lane);
                if (lane < 8) {
                    const int j = gj0 + lane;
                    const float g = 1.0f / (1.0f + __expf(-(sum + bgj)));
                    if (gj0 < HH)
                        stc(rhl + (size_t)b * HH + j, g * hl[(size_t)b * HH + j]);
                    else
                        stc(uul + (size_t)b * HH + (j - HH), g);
                }
            }
        }
        gbar(bar, tgt); tgt += NBLK;

        // ---------------- phase B: candidate + update ----------------
        if (active) {
#pragma unroll 2
            for (int bi = 0; bi < 8; ++bi) {
                const int b = w * 8 + bi;
                const float* inrow = l ? (y0 + ((size_t)((tt & 1) * BB + b)) * HH)
                                       : (x + ((size_t)b * TT + tt) * HH);
                const float* vp = (lane < 32) ? (inrow + lane * 16)
                                              : (rhl + (size_t)b * HH + (lane - 32) * 16);
                const float4 a0 = ((const float4*)vp)[0];
                const float4 a1 = ((const float4*)vp)[1];
                const float4 a2 = ((const float4*)vp)[2];
                const float4 a3 = ((const float4*)vp)[3];
                const float s0 = dot16(a0, a1, a2, a3, WC[0]);
                const float s1 = dot16(a0, a1, a2, a3, WC[1]);
                const float s2 = dot16(a0, a1, a2, a3, WC[2]);
                const float s3 = dot16(a0, a1, a2, a3, WC[3]);
                const float sum = red4(s0, s1, s2, s3, lane);
                if (lane < 4) {
                    const int m = cj0 + lane;
                    const float c = tanhf(sum + bcm);
                    const float u = uul[(size_t)b * HH + m];
                    const float hold = hl[(size_t)b * HH + m];
                    const bool act = tt < seq_lens[b];
                    const float hn = u * hold + (1.0f - u) * c;
                    stc(hl + (size_t)b * HH + m, act ? hn : hold);
                    const float yv = act ? hn : 0.0f;
                    if (l == 0)
                        stc(y0 + ((size_t)((tt & 1) * BB + b)) * HH + m, yv);
                    else
                        out[((size_t)b * TT + tt) * HH + m] = yv;
                }
            }
        }
        gbar(bar, tgt); tgt += NBLK;
    }
}

extern "C" void kernel_launch(void* const* d_in, const int* in_sizes, int n_in,
                              void* d_out, int out_size, void* d_ws, size_t ws_size,
                              hipStream_t stream) {
    const float* x = (const float*)d_in[0];
    const int* seq_lens = (const int*)d_in[1];
    const float* Wg = (const float*)d_in[2];
    const float* bg = (const float*)d_in[3];
    const float* Wc = (const float*)d_in[4];
    const float* bc = (const float*)d_in[5];
    float* out = (float*)d_out;
    float* ws = (float*)d_ws;

    float* WgT = ws + 131088;
    float* WcT = ws + 131088 + 2097152;

    // zero h0,h1 (+ scratch state + barrier counter) every launch so graph
    // replays are deterministic.
    hipMemsetAsync(ws, 0, (131072 + 16) * sizeof(float), stream);

    transpose_k<1024, 1024><<<1024, 256, 0, stream>>>(Wg, WgT);
    transpose_k<1024, 1024><<<1024, 256, 0, stream>>>(Wg + 1024 * 1024, WgT + 1024 * 1024);
    transpose_k<1024, 512><<<512, 256, 0, stream>>>(Wc, WcT);
    transpose_k<1024, 512><<<512, 256, 0, stream>>>(Wc + 1024 * 512, WcT + 512 * 1024);

    rnn_persist<<<NBLK, 256, 0, stream>>>(x, seq_lens, WgT, bg, WcT, bc, out, ws);
}